// Round 1
// baseline (403.518 us; speedup 1.0000x reference)
//
#include <hip/hip_runtime.h>
#include <hip/hip_bf16.h>

#define B_ 4
#define Q_ 64
#define C_ 384
#define H_ 6
#define L_ 5
#define P_ 4
#define DFF_ 1024
#define EXTRA_ 128
#define DH_ 64
#define S_ 66836

// ---------------- generic linear: out[row, j] = bias[j] + in[row,:] . W[j,:] ----------------
__global__ void linear_kernel(const float* __restrict__ in, const float* __restrict__ W,
                              const float* __restrict__ bias, float* __restrict__ out,
                              int K, int OUT, int relu) {
    int row = blockIdx.y;
    int j = blockIdx.x * blockDim.x + threadIdx.x;
    if (j >= OUT) return;
    const float* ip = in + (size_t)row * K;
    const float* wp = W + (size_t)j * K;
    float acc = bias[j];
#pragma unroll 4
    for (int k = 0; k < K; k += 4) {
        float4 a = *reinterpret_cast<const float4*>(ip + k);
        float4 w = *reinterpret_cast<const float4*>(wp + k);
        acc += a.x * w.x + a.y * w.y + a.z * w.z + a.w * w.w;
    }
    if (relu) acc = fmaxf(acc, 0.f);
    out[(size_t)row * OUT + j] = acc;
}

// ---------------- self attention: qkv (B*Q, 3C), 64 keys ----------------
__global__ void self_attn_kernel(const float* __restrict__ qkv, float* __restrict__ o) {
    int qi = blockIdx.x, h = blockIdx.y, b = blockIdx.z;
    int t = threadIdx.x; // 0..63
    __shared__ float sq[64];
    __shared__ float sa[64];
    int row = b * Q_ + qi;
    sq[t] = qkv[(size_t)row * (3 * C_) + h * DH_ + t];
    __syncthreads();
    const float* krow = qkv + (size_t)(b * Q_ + t) * (3 * C_) + C_ + h * DH_;
    float s = 0.f;
#pragma unroll 8
    for (int d = 0; d < DH_; ++d) s += sq[d] * krow[d];
    s *= 0.125f;
    float m = s;
    for (int off = 32; off; off >>= 1) m = fmaxf(m, __shfl_xor(m, off));
    float e = __expf(s - m);
    float sum = e;
    for (int off = 32; off; off >>= 1) sum += __shfl_xor(sum, off);
    sa[t] = e / sum;
    __syncthreads();
    float acc = 0.f;
#pragma unroll 4
    for (int k = 0; k < 64; ++k) {
        acc += sa[k] * qkv[(size_t)(b * Q_ + k) * (3 * C_) + 2 * C_ + h * DH_ + t];
    }
    o[(size_t)row * C_ + h * DH_ + t] = acc;
}

// ---------------- cross attention: q (B*Q, C), kv (B*EXTRA, 2C), 128 keys ----------------
__global__ void cross_attn_kernel(const float* __restrict__ qb, const float* __restrict__ kv,
                                  float* __restrict__ o) {
    int qi = blockIdx.x, h = blockIdx.y, b = blockIdx.z;
    int t = threadIdx.x; // 0..63
    __shared__ float sq[64];
    __shared__ float sa[128];
    int row = b * Q_ + qi;
    sq[t] = qb[(size_t)row * C_ + h * DH_ + t];
    __syncthreads();
    const float* k0 = kv + (size_t)(b * EXTRA_ + t) * (2 * C_) + h * DH_;
    const float* k1 = kv + (size_t)(b * EXTRA_ + t + 64) * (2 * C_) + h * DH_;
    float s0 = 0.f, s1 = 0.f;
#pragma unroll 8
    for (int d = 0; d < DH_; ++d) { float qd = sq[d]; s0 += qd * k0[d]; s1 += qd * k1[d]; }
    s0 *= 0.125f; s1 *= 0.125f;
    float m = fmaxf(s0, s1);
    for (int off = 32; off; off >>= 1) m = fmaxf(m, __shfl_xor(m, off));
    float e0 = __expf(s0 - m), e1 = __expf(s1 - m);
    float sum = e0 + e1;
    for (int off = 32; off; off >>= 1) sum += __shfl_xor(sum, off);
    sa[t] = e0 / sum; sa[t + 64] = e1 / sum;
    __syncthreads();
    float acc = 0.f;
#pragma unroll 4
    for (int k = 0; k < 128; ++k) {
        acc += sa[k] * kv[(size_t)(b * EXTRA_ + k) * (2 * C_) + C_ + h * DH_ + t];
    }
    o[(size_t)row * C_ + h * DH_ + t] = acc;
}

// ---------------- residual add + layernorm; one wave per row ----------------
__global__ void add_ln_kernel(const float* __restrict__ x, const float* __restrict__ r,
                              const float* __restrict__ g, const float* __restrict__ bgb,
                              float* __restrict__ out) {
    int row = blockIdx.x;
    int t = threadIdx.x; // 64
    float v[6];
    float mean = 0.f;
#pragma unroll
    for (int i = 0; i < 6; ++i) {
        int c = t + i * 64;
        v[i] = x[(size_t)row * C_ + c] + r[(size_t)row * C_ + c];
        mean += v[i];
    }
    for (int off = 32; off; off >>= 1) mean += __shfl_xor(mean, off);
    mean *= (1.f / C_);
    float var = 0.f;
#pragma unroll
    for (int i = 0; i < 6; ++i) { float d = v[i] - mean; var += d * d; }
    for (int off = 32; off; off >>= 1) var += __shfl_xor(var, off);
    var *= (1.f / C_);
    float inv = rsqrtf(var + 1e-5f);
#pragma unroll
    for (int i = 0; i < 6; ++i) {
        int c = t + i * 64;
        out[(size_t)row * C_ + c] = (v[i] - mean) * inv * g[c] + bgb[c];
    }
}

// ---------------- softmax over 20 (L*P) per (b,q,h) row ----------------
__global__ void softmax20_kernel(float* __restrict__ a) {
    int i = blockIdx.x * blockDim.x + threadIdx.x;
    if (i >= B_ * Q_ * H_) return;
    float* p = a + (size_t)i * (L_ * P_);
    float m = -1e30f;
#pragma unroll
    for (int k = 0; k < 20; ++k) m = fmaxf(m, p[k]);
    float s = 0.f;
#pragma unroll
    for (int k = 0; k < 20; ++k) { p[k] = __expf(p[k] - m); s += p[k]; }
    float inv = 1.f / s;
#pragma unroll
    for (int k = 0; k < 20; ++k) p[k] *= inv;
}

// ---------------- deformable gather: accumulate weighted src rows per (b,q,h) ----------------
__global__ void ms_gather_kernel(const float* __restrict__ src, const float* __restrict__ refp,
                                 const float* __restrict__ vr, const float* __restrict__ off,
                                 const float* __restrict__ aw, float* __restrict__ agg,
                                 float* __restrict__ wsum) {
    int h = blockIdx.x, qi = blockIdx.y, b = blockIdx.z;
    int t = threadIdx.x; // 0..127 -> columns t, t+128, t+256
    const int lsi[5] = {0, 196, 980, 4116, 16660};
    const int whl[5] = {14, 28, 56, 112, 224};
    int row = b * Q_ + qi;
    float acc0 = 0.f, acc1 = 0.f, acc2 = 0.f;
    float wsm = 0.f;
    const float rx = refp[row * 2 + 0], ry = refp[row * 2 + 1];
    for (int l = 0; l < L_; ++l) {
        float Wf = (float)whl[l], Hf = (float)whl[l];
        float rpx = rx * vr[(b * L_ + l) * 2 + 0];
        float rpy = ry * vr[(b * L_ + l) * 2 + 1];
#pragma unroll
        for (int p = 0; p < P_; ++p) {
            int oidx = row * (H_ * L_ * P_ * 2) + ((h * L_ + l) * P_ + p) * 2;
            float ox = off[oidx + 0];
            float oy = off[oidx + 1];
            float locx = rpx + ox / Wf;
            float locy = rpy + oy / Hf;
            float x = locx * Wf - 0.5f;
            float y = locy * Hf - 0.5f;
            float x0 = floorf(x), y0 = floorf(y);
            float wx = x - x0, wy = y - y0;
            float a = aw[(size_t)(row * H_ + h) * 20 + l * P_ + p];
            float cw[4] = {(1.f - wx) * (1.f - wy), wx * (1.f - wy), (1.f - wx) * wy, wx * wy};
            float cx[4] = {x0, x0 + 1.f, x0, x0 + 1.f};
            float cy[4] = {y0, y0, y0 + 1.f, y0 + 1.f};
#pragma unroll
            for (int c2 = 0; c2 < 4; ++c2) {
                bool valid = (cx[c2] >= 0.f) && (cx[c2] <= Wf - 1.f) &&
                             (cy[c2] >= 0.f) && (cy[c2] <= Hf - 1.f);
                if (!valid) continue; // wave-uniform (same for all lanes in block)
                float w = a * cw[c2];
                wsm += w;
                int xi = (int)cx[c2], yi = (int)cy[c2];
                const float* sp = src + ((size_t)b * S_ + lsi[l] + yi * whl[l] + xi) * C_;
                acc0 += w * sp[t];
                acc1 += w * sp[t + 128];
                acc2 += w * sp[t + 256];
            }
        }
    }
    float* ap = agg + ((size_t)row * H_ + h) * C_;
    ap[t] = acc0; ap[t + 128] = acc1; ap[t + 256] = acc2;
    if (t == 0) wsum[row * H_ + h] = wsm;
}

// ---------------- value projection of aggregated rows ----------------
__global__ void ms_valproj_kernel(const float* __restrict__ agg, const float* __restrict__ wsum,
                                  const float* __restrict__ Wv, const float* __restrict__ bv,
                                  float* __restrict__ out) {
    int row = blockIdx.y;
    int j = blockIdx.x * blockDim.x + threadIdx.x; // 0..383
    if (j >= C_) return;
    int h = j / DH_;
    const float* ap = agg + ((size_t)row * H_ + h) * C_;
    const float* wp = Wv + (size_t)j * C_;
    float acc = 0.f;
#pragma unroll 4
    for (int k = 0; k < C_; k += 4) {
        float4 a4 = *reinterpret_cast<const float4*>(ap + k);
        float4 w4 = *reinterpret_cast<const float4*>(wp + k);
        acc += a4.x * w4.x + a4.y * w4.y + a4.z * w4.z + a4.w * w4.w;
    }
    out[(size_t)row * C_ + j] = acc + bv[j] * wsum[row * H_ + h];
}

extern "C" void kernel_launch(void* const* d_in, const int* in_sizes, int n_in,
                              void* d_out, int out_size, void* d_ws, size_t ws_size,
                              hipStream_t stream) {
    const float* tgt   = (const float*)d_in[0];
    const float* refp  = (const float*)d_in[1];
    const float* src   = (const float*)d_in[2];
    const float* extra = (const float*)d_in[3];
    const float* vr    = (const float*)d_in[4];
    const float* sa_in_w  = (const float*)d_in[7];
    const float* sa_out_w = (const float*)d_in[8];
    const float* ea_in_w  = (const float*)d_in[9];
    const float* ea_out_w = (const float*)d_in[10];
    const float* ms_off_w = (const float*)d_in[11];
    const float* ms_attn_w= (const float*)d_in[12];
    const float* ms_val_w = (const float*)d_in[13];
    const float* ms_out_w = (const float*)d_in[14];
    const float* ffn_w1   = (const float*)d_in[15];
    const float* ffn_w2   = (const float*)d_in[16];
    const float* sa_in_b  = (const float*)d_in[17];
    const float* sa_out_b = (const float*)d_in[18];
    const float* ea_in_b  = (const float*)d_in[19];
    const float* ea_out_b = (const float*)d_in[20];
    const float* ms_attn_b= (const float*)d_in[21];
    const float* ms_val_b = (const float*)d_in[22];
    const float* ms_out_b = (const float*)d_in[23];
    const float* ffn_b1   = (const float*)d_in[24];
    const float* ffn_b2   = (const float*)d_in[25];
    const float* ln2_b    = (const float*)d_in[26];
    const float* lne_b    = (const float*)d_in[27];
    const float* ln1_b    = (const float*)d_in[28];
    const float* ln3_b    = (const float*)d_in[29];
    const float* ms_off_b = (const float*)d_in[30];
    const float* ln2_g    = (const float*)d_in[31];
    const float* lne_g    = (const float*)d_in[32];
    const float* ln1_g    = (const float*)d_in[33];
    const float* ln3_g    = (const float*)d_in[34];

    float* ws = (float*)d_ws;
    float* s0 = ws;                 // 589824 (qkv, later agg)
    float* s1 = ws + 589824;        // 393216 (ea kv, later ffn h1)
    float* s2 = ws + 983040;        // 98304
    float* s3 = ws + 1081344;       // 98304
    float* s4 = ws + 1179648;       // 98304
    float* s5 = ws + 1277952;       // 98304
    float* s6 = ws + 1376256;       // 61440 (off)
    float* s7 = ws + 1437696;       // 30720 (aw)
    float* s8 = ws + 1468416;       // 1536  (wsum)

    const int N = B_ * Q_; // 256 rows
    dim3 blk128(128);

    // 1. SA qkv projection
    linear_kernel<<<dim3((3 * C_ + 127) / 128, N), blk128, 0, stream>>>(tgt, sa_in_w, sa_in_b, s0, C_, 3 * C_, 0);
    // 2. self attention
    self_attn_kernel<<<dim3(Q_, H_, B_), dim3(64), 0, stream>>>(s0, s2);
    // 3. SA out projection
    linear_kernel<<<dim3(3, N), blk128, 0, stream>>>(s2, sa_out_w, sa_out_b, s3, C_, C_, 0);
    // 4. tgt1 = LN(tgt + t2)
    add_ln_kernel<<<dim3(N), dim3(64), 0, stream>>>(s3, tgt, ln2_g, ln2_b, s4);
    // 5. EA q projection
    linear_kernel<<<dim3(3, N), blk128, 0, stream>>>(s4, ea_in_w, ea_in_b, s2, C_, C_, 0);
    // 6. EA kv projection (rows C..3C of ea_in_w)
    linear_kernel<<<dim3(6, B_ * EXTRA_), blk128, 0, stream>>>(extra, ea_in_w + (size_t)C_ * C_, ea_in_b + C_, s1, C_, 2 * C_, 0);
    // 7. cross attention
    cross_attn_kernel<<<dim3(Q_, H_, B_), dim3(64), 0, stream>>>(s2, s1, s3);
    // 8. EA out projection
    linear_kernel<<<dim3(3, N), blk128, 0, stream>>>(s3, ea_out_w, ea_out_b, s2, C_, C_, 0);
    // 9. tgt2 = LN(tgt1 + t2)
    add_ln_kernel<<<dim3(N), dim3(64), 0, stream>>>(s2, s4, lne_g, lne_b, s5);
    // 10. sampling offsets
    linear_kernel<<<dim3(2, N), blk128, 0, stream>>>(s5, ms_off_w, ms_off_b, s6, C_, H_ * L_ * P_ * 2, 0);
    // 11. attention-weight logits
    linear_kernel<<<dim3(1, N), blk128, 0, stream>>>(s5, ms_attn_w, ms_attn_b, s7, C_, H_ * L_ * P_, 0);
    // 12. softmax over L*P per (b,q,h)
    softmax20_kernel<<<dim3(6), dim3(256), 0, stream>>>(s7);
    // 13. deformable gather-aggregate
    ms_gather_kernel<<<dim3(H_, Q_, B_), blk128, 0, stream>>>(src, refp, vr, s6, s7, s0, s8);
    // 14. value projection of aggregates
    ms_valproj_kernel<<<dim3(3, N), blk128, 0, stream>>>(s0, s8, ms_val_w, ms_val_b, s2);
    // 15. ms out projection
    linear_kernel<<<dim3(3, N), blk128, 0, stream>>>(s2, ms_out_w, ms_out_b, s3, C_, C_, 0);
    // 16. tgt3 = LN(tgt2 + t2)
    add_ln_kernel<<<dim3(N), dim3(64), 0, stream>>>(s3, s5, ln1_g, ln1_b, s4);
    // 17. FFN layer 1 (relu)
    linear_kernel<<<dim3(8, N), blk128, 0, stream>>>(s4, ffn_w1, ffn_b1, s1, C_, DFF_, 1);
    // 18. FFN layer 2
    linear_kernel<<<dim3(3, N), blk128, 0, stream>>>(s1, ffn_w2, ffn_b2, s2, DFF_, C_, 0);
    // 19. out = LN(tgt3 + t2)
    add_ln_kernel<<<dim3(N), dim3(64), 0, stream>>>(s2, s4, ln3_g, ln3_b, (float*)d_out);
}

// Round 2
// 282.388 us; speedup vs baseline: 1.4289x; 1.4289x over previous
//
#include <hip/hip_runtime.h>
#include <hip/hip_bf16.h>

#define B_ 4
#define Q_ 64
#define C_ 384
#define H_ 6
#define L_ 5
#define P_ 4
#define DFF_ 1024
#define EXTRA_ 128
#define DH_ 64
#define S_ 66836

__device__ __forceinline__ float wave_sum(float v) {
    for (int off = 32; off; off >>= 1) v += __shfl_xor(v, off);
    return v;
}
__device__ __forceinline__ float wave_max(float v) {
    for (int off = 32; off; off >>= 1) v = fmaxf(v, __shfl_xor(v, off));
    return v;
}
// block reduce over 6 waves (384 threads)
__device__ __forceinline__ float block_sum6(float v, float* red, int t) {
    v = wave_sum(v);
    if ((t & 63) == 0) red[t >> 6] = v;
    __syncthreads();
    float s = red[0] + red[1] + red[2] + red[3] + red[4] + red[5];
    __syncthreads();
    return s;
}

// ---------- 4-row-tiled linear: out[r, j] = bias[j] + in[r,:] . W[j,:] ----------
__global__ void linear4_kernel(const float* __restrict__ in, const float* __restrict__ W,
                               const float* __restrict__ bias, float* __restrict__ out,
                               int K, int OUT, int relu) {
    int j = blockIdx.x * blockDim.x + threadIdx.x;
    int r0 = blockIdx.y * 4;
    if (j >= OUT) return;
    const float* wp = W + (size_t)j * K;
    const float* i0 = in + (size_t)r0 * K;
    const float* i1 = i0 + K;
    const float* i2 = i1 + K;
    const float* i3 = i2 + K;
    float a0 = 0.f, a1 = 0.f, a2 = 0.f, a3 = 0.f;
#pragma unroll 4
    for (int k = 0; k < K; k += 4) {
        float4 w = *reinterpret_cast<const float4*>(wp + k);
        float4 x0 = *reinterpret_cast<const float4*>(i0 + k);
        float4 x1 = *reinterpret_cast<const float4*>(i1 + k);
        float4 x2 = *reinterpret_cast<const float4*>(i2 + k);
        float4 x3 = *reinterpret_cast<const float4*>(i3 + k);
        a0 += w.x * x0.x + w.y * x0.y + w.z * x0.z + w.w * x0.w;
        a1 += w.x * x1.x + w.y * x1.y + w.z * x1.z + w.w * x1.w;
        a2 += w.x * x2.x + w.y * x2.y + w.z * x2.z + w.w * x2.w;
        a3 += w.x * x3.x + w.y * x3.y + w.z * x3.z + w.w * x3.w;
    }
    float bb = bias[j];
    a0 += bb; a1 += bb; a2 += bb; a3 += bb;
    if (relu) { a0 = fmaxf(a0, 0.f); a1 = fmaxf(a1, 0.f); a2 = fmaxf(a2, 0.f); a3 = fmaxf(a3, 0.f); }
    out[(size_t)(r0 + 0) * OUT + j] = a0;
    out[(size_t)(r0 + 1) * OUT + j] = a1;
    out[(size_t)(r0 + 2) * OUT + j] = a2;
    out[(size_t)(r0 + 3) * OUT + j] = a3;
}

// ---------- fused self-attention + out-proj + residual + LN (one block per (b,q)) ----------
__global__ void sa_fused_kernel(const float* __restrict__ qkv, const float* __restrict__ res,
                                const float* __restrict__ Wo, const float* __restrict__ bo,
                                const float* __restrict__ g, const float* __restrict__ beta,
                                float* __restrict__ out) {
    int row = blockIdx.x;
    int b = row >> 6;
    int t = threadIdx.x;            // 0..383
    int h = t >> 6, lane = t & 63;
    __shared__ float q_lds[384], a_lds[384], o_lds[384], red[8];
    q_lds[t] = qkv[(size_t)row * 1152 + t];
    __syncthreads();
    const float* krow = qkv + (size_t)(b * 64 + lane) * 1152 + 384 + h * 64;
    float s = 0.f;
#pragma unroll 8
    for (int d = 0; d < 64; ++d) s += q_lds[h * 64 + d] * krow[d];
    s *= 0.125f;
    float m = wave_max(s);
    float e = __expf(s - m);
    float sum = wave_sum(e);
    a_lds[t] = e / sum;
    __syncthreads();
    float acc = 0.f;
#pragma unroll 4
    for (int k = 0; k < 64; ++k)
        acc += a_lds[h * 64 + k] * qkv[(size_t)(b * 64 + k) * 1152 + 768 + h * 64 + lane];
    o_lds[t] = acc;
    __syncthreads();
    const float* wp = Wo + (size_t)t * 384;
    float v = bo[t] + res[(size_t)row * 384 + t];
#pragma unroll 4
    for (int k = 0; k < 384; k += 4) {
        float4 w = *reinterpret_cast<const float4*>(wp + k);
        v += w.x * o_lds[k] + w.y * o_lds[k + 1] + w.z * o_lds[k + 2] + w.w * o_lds[k + 3];
    }
    float mean = block_sum6(v, red, t) * (1.f / 384.f);
    float d = v - mean;
    float var = block_sum6(d * d, red, t) * (1.f / 384.f);
    out[(size_t)row * 384 + t] = d * rsqrtf(var + 1e-5f) * g[t] + beta[t];
}

// ---------- fused EA: q-proj + cross-attn(128 keys) + out-proj + residual + LN ----------
__global__ void ea_fused_kernel(const float* __restrict__ t1, const float* __restrict__ kv,
                                const float* __restrict__ Wq, const float* __restrict__ bq,
                                const float* __restrict__ Wo, const float* __restrict__ bo,
                                const float* __restrict__ g, const float* __restrict__ beta,
                                float* __restrict__ out) {
    int row = blockIdx.x;
    int b = row >> 6;
    int t = threadIdx.x;
    int h = t >> 6, lane = t & 63;
    __shared__ float in_lds[384], q_lds[384], a_lds[768], o_lds[384], red[8];
    in_lds[t] = t1[(size_t)row * 384 + t];
    __syncthreads();
    const float* wq = Wq + (size_t)t * 384;
    float qv = bq[t];
#pragma unroll 4
    for (int k = 0; k < 384; k += 4) {
        float4 w = *reinterpret_cast<const float4*>(wq + k);
        qv += w.x * in_lds[k] + w.y * in_lds[k + 1] + w.z * in_lds[k + 2] + w.w * in_lds[k + 3];
    }
    q_lds[t] = qv;
    __syncthreads();
    const float* k0 = kv + (size_t)(b * 128 + lane) * 768 + h * 64;
    const float* k1 = k0 + (size_t)64 * 768;
    float s0 = 0.f, s1 = 0.f;
#pragma unroll 8
    for (int d = 0; d < 64; ++d) { float qd = q_lds[h * 64 + d]; s0 += qd * k0[d]; s1 += qd * k1[d]; }
    s0 *= 0.125f; s1 *= 0.125f;
    float m = wave_max(fmaxf(s0, s1));
    float e0 = __expf(s0 - m), e1 = __expf(s1 - m);
    float sum = wave_sum(e0 + e1);
    a_lds[h * 128 + lane] = e0 / sum;
    a_lds[h * 128 + 64 + lane] = e1 / sum;
    __syncthreads();
    float acc = 0.f;
#pragma unroll 4
    for (int k = 0; k < 128; ++k)
        acc += a_lds[h * 128 + k] * kv[(size_t)(b * 128 + k) * 768 + 384 + h * 64 + lane];
    o_lds[t] = acc;
    __syncthreads();
    const float* wo = Wo + (size_t)t * 384;
    float v = bo[t] + in_lds[t];
#pragma unroll 4
    for (int k = 0; k < 384; k += 4) {
        float4 w = *reinterpret_cast<const float4*>(wo + k);
        v += w.x * o_lds[k] + w.y * o_lds[k + 1] + w.z * o_lds[k + 2] + w.w * o_lds[k + 3];
    }
    float mean = block_sum6(v, red, t) * (1.f / 384.f);
    float d = v - mean;
    float var = block_sum6(d * d, red, t) * (1.f / 384.f);
    out[(size_t)row * 384 + t] = d * rsqrtf(var + 1e-5f) * g[t] + beta[t];
}

// ---------- fused offsets + attn logits + per-head softmax20 ----------
__global__ void ms_prep_kernel(const float* __restrict__ t2, const float* __restrict__ Woff,
                               const float* __restrict__ boff, const float* __restrict__ Wa,
                               const float* __restrict__ ba, float* __restrict__ offs,
                               float* __restrict__ aw) {
    int row = blockIdx.x;
    int t = threadIdx.x;  // 384
    __shared__ float in_lds[384], lg[120];
    in_lds[t] = t2[(size_t)row * 384 + t];
    __syncthreads();
    if (t < 240) {
        const float* wp = Woff + (size_t)t * 384;
        float v = boff[t];
#pragma unroll 4
        for (int k = 0; k < 384; k += 4) {
            float4 w = *reinterpret_cast<const float4*>(wp + k);
            v += w.x * in_lds[k] + w.y * in_lds[k + 1] + w.z * in_lds[k + 2] + w.w * in_lds[k + 3];
        }
        offs[(size_t)row * 240 + t] = v;
    } else if (t < 360) {
        int j = t - 240;
        const float* wp = Wa + (size_t)j * 384;
        float v = ba[j];
#pragma unroll 4
        for (int k = 0; k < 384; k += 4) {
            float4 w = *reinterpret_cast<const float4*>(wp + k);
            v += w.x * in_lds[k] + w.y * in_lds[k + 1] + w.z * in_lds[k + 2] + w.w * in_lds[k + 3];
        }
        lg[j] = v;
    }
    __syncthreads();
    if (t < 6) {
        float m = -1e30f;
#pragma unroll
        for (int k = 0; k < 20; ++k) m = fmaxf(m, lg[t * 20 + k]);
        float e[20]; float s = 0.f;
#pragma unroll
        for (int k = 0; k < 20; ++k) { e[k] = __expf(lg[t * 20 + k] - m); s += e[k]; }
        float inv = 1.f / s;
#pragma unroll
        for (int k = 0; k < 20; ++k) aw[(size_t)row * 120 + t * 20 + k] = e[k] * inv;
    }
}

// ---------- deformable gather: one block per (l, h, row); partial agg per level ----------
__global__ void ms_gather_kernel(const float* __restrict__ src, const float* __restrict__ refp,
                                 const float* __restrict__ vr, const float* __restrict__ offs,
                                 const float* __restrict__ aw, float* __restrict__ pagg,
                                 float* __restrict__ pwsum) {
    int l = blockIdx.x, h = blockIdx.y, row = blockIdx.z;
    int b = row >> 6;
    int t = threadIdx.x;  // 0..127
    const int lsi[5] = {0, 196, 980, 4116, 16660};
    const int whl[5] = {14, 28, 56, 112, 224};
    int wh = whl[l];
    float Wf = (float)wh;
    float rpx = refp[row * 2 + 0] * vr[(b * 5 + l) * 2 + 0];
    float rpy = refp[row * 2 + 1] * vr[(b * 5 + l) * 2 + 1];
    const float* srcb = src + ((size_t)b * S_ + lsi[l]) * 384;
    float acc0 = 0.f, acc1 = 0.f, acc2 = 0.f, wsm = 0.f;
#pragma unroll
    for (int p = 0; p < 4; ++p) {
        int oidx = row * 240 + ((h * 5 + l) * 4 + p) * 2;
        float ox = offs[oidx], oy = offs[oidx + 1];
        float locx = rpx + ox / Wf;
        float locy = rpy + oy / Wf;
        float x = locx * Wf - 0.5f;
        float y = locy * Wf - 0.5f;
        float x0 = floorf(x), y0 = floorf(y);
        float wx = x - x0, wy = y - y0;
        float a = aw[row * 120 + h * 20 + l * 4 + p];
        float cw[4] = {(1.f - wx) * (1.f - wy), wx * (1.f - wy), (1.f - wx) * wy, wx * wy};
        float cx[4] = {x0, x0 + 1.f, x0, x0 + 1.f};
        float cy[4] = {y0, y0, y0 + 1.f, y0 + 1.f};
#pragma unroll
        for (int c2 = 0; c2 < 4; ++c2) {
            bool valid = (cx[c2] >= 0.f) && (cx[c2] <= Wf - 1.f) &&
                         (cy[c2] >= 0.f) && (cy[c2] <= Wf - 1.f);
            if (!valid) continue;  // block-uniform
            float w = a * cw[c2];
            wsm += w;
            int xi = (int)cx[c2], yi = (int)cy[c2];
            const float* sp = srcb + (size_t)(yi * wh + xi) * 384;
            acc0 += w * sp[t];
            acc1 += w * sp[t + 128];
            acc2 += w * sp[t + 256];
        }
    }
    float* ap = pagg + ((size_t)(row * 6 + h) * 5 + l) * 384;
    ap[t] = acc0; ap[t + 128] = acc1; ap[t + 256] = acc2;
    if (t == 0) pwsum[(row * 6 + h) * 5 + l] = wsm;
}

// ---------- fused: level-reduce + value-proj + out-proj + residual + LN ----------
__global__ void ms_valout_kernel(const float* __restrict__ pagg, const float* __restrict__ pwsum,
                                 const float* __restrict__ Wv, const float* __restrict__ bv,
                                 const float* __restrict__ Wo, const float* __restrict__ bo,
                                 const float* __restrict__ t2, const float* __restrict__ g,
                                 const float* __restrict__ beta, float* __restrict__ out) {
    int row = blockIdx.x;
    int t = threadIdx.x;  // 384
    __shared__ float agg[2304], val[384], wsum[6], red[8];
#pragma unroll
    for (int e = 0; e < 6; ++e) {
        int idx = t + e * 384;
        int hh = idx / 384, col = idx % 384;
        const float* pp = pagg + ((size_t)(row * 6 + hh) * 5) * 384 + col;
        agg[idx] = pp[0] + pp[384] + pp[768] + pp[1152] + pp[1536];
    }
    if (t < 6) {
        const float* pw = pwsum + (row * 6 + t) * 5;
        wsum[t] = pw[0] + pw[1] + pw[2] + pw[3] + pw[4];
    }
    __syncthreads();
    int h = t >> 6;
    const float* wp = Wv + (size_t)t * 384;
    const float* ag = agg + h * 384;
    float v = bv[t] * wsum[h];
#pragma unroll 4
    for (int k = 0; k < 384; k += 4) {
        float4 w = *reinterpret_cast<const float4*>(wp + k);
        v += w.x * ag[k] + w.y * ag[k + 1] + w.z * ag[k + 2] + w.w * ag[k + 3];
    }
    val[t] = v;
    __syncthreads();
    const float* wo = Wo + (size_t)t * 384;
    float o = bo[t] + t2[(size_t)row * 384 + t];
#pragma unroll 4
    for (int k = 0; k < 384; k += 4) {
        float4 w = *reinterpret_cast<const float4*>(wo + k);
        o += w.x * val[k] + w.y * val[k + 1] + w.z * val[k + 2] + w.w * val[k + 3];
    }
    float mean = block_sum6(o, red, t) * (1.f / 384.f);
    float d = o - mean;
    float var = block_sum6(d * d, red, t) * (1.f / 384.f);
    out[(size_t)row * 384 + t] = d * rsqrtf(var + 1e-5f) * g[t] + beta[t];
}

// ---------- residual add + layernorm; one wave per row ----------
__global__ void add_ln_kernel(const float* __restrict__ x, const float* __restrict__ r,
                              const float* __restrict__ g, const float* __restrict__ bgb,
                              float* __restrict__ out) {
    int row = blockIdx.x;
    int t = threadIdx.x;  // 64
    float v[6];
    float mean = 0.f;
#pragma unroll
    for (int i = 0; i < 6; ++i) {
        int c = t + i * 64;
        v[i] = x[(size_t)row * C_ + c] + r[(size_t)row * C_ + c];
        mean += v[i];
    }
    mean = wave_sum(mean) * (1.f / C_);
    float var = 0.f;
#pragma unroll
    for (int i = 0; i < 6; ++i) { float d = v[i] - mean; var += d * d; }
    var = wave_sum(var) * (1.f / C_);
    float inv = rsqrtf(var + 1e-5f);
#pragma unroll
    for (int i = 0; i < 6; ++i) {
        int c = t + i * 64;
        out[(size_t)row * C_ + c] = (v[i] - mean) * inv * g[c] + bgb[c];
    }
}

extern "C" void kernel_launch(void* const* d_in, const int* in_sizes, int n_in,
                              void* d_out, int out_size, void* d_ws, size_t ws_size,
                              hipStream_t stream) {
    const float* tgt   = (const float*)d_in[0];
    const float* refp  = (const float*)d_in[1];
    const float* src   = (const float*)d_in[2];
    const float* extra = (const float*)d_in[3];
    const float* vr    = (const float*)d_in[4];
    const float* sa_in_w  = (const float*)d_in[7];
    const float* sa_out_w = (const float*)d_in[8];
    const float* ea_in_w  = (const float*)d_in[9];
    const float* ea_out_w = (const float*)d_in[10];
    const float* ms_off_w = (const float*)d_in[11];
    const float* ms_attn_w= (const float*)d_in[12];
    const float* ms_val_w = (const float*)d_in[13];
    const float* ms_out_w = (const float*)d_in[14];
    const float* ffn_w1   = (const float*)d_in[15];
    const float* ffn_w2   = (const float*)d_in[16];
    const float* sa_in_b  = (const float*)d_in[17];
    const float* sa_out_b = (const float*)d_in[18];
    const float* ea_in_b  = (const float*)d_in[19];
    const float* ea_out_b = (const float*)d_in[20];
    const float* ms_attn_b= (const float*)d_in[21];
    const float* ms_val_b = (const float*)d_in[22];
    const float* ms_out_b = (const float*)d_in[23];
    const float* ffn_b1   = (const float*)d_in[24];
    const float* ffn_b2   = (const float*)d_in[25];
    const float* ln2_b    = (const float*)d_in[26];
    const float* lne_b    = (const float*)d_in[27];
    const float* ln1_b    = (const float*)d_in[28];
    const float* ln3_b    = (const float*)d_in[29];
    const float* ms_off_b = (const float*)d_in[30];
    const float* ln2_g    = (const float*)d_in[31];
    const float* lne_g    = (const float*)d_in[32];
    const float* ln1_g    = (const float*)d_in[33];
    const float* ln3_g    = (const float*)d_in[34];

    float* ws = (float*)d_ws;
    float* s_qkv  = ws;                    // 294912
    float* s_eakv = s_qkv + 294912;        // 393216
    float* s_t1   = s_eakv + 393216;       // 98304
    float* s_t2   = s_t1 + 98304;          // 98304
    float* s_t3   = s_t2 + 98304;          // 98304
    float* s_off  = s_t3 + 98304;          // 61440
    float* s_aw   = s_off + 61440;         // 30720
    float* s_pagg = s_aw + 30720;          // 2949120
    float* s_pws  = s_pagg + 2949120;      // 7680
    float* s_h1   = s_pws + 7680;          // 262144
    float* s_f2   = s_h1 + 262144;         // 98304

    // 1. SA qkv projection (256 x 1152)
    linear4_kernel<<<dim3(9, 64), dim3(128), 0, stream>>>(tgt, sa_in_w, sa_in_b, s_qkv, C_, 3 * C_, 0);
    // 2. EA kv projection (512 x 768) — independent of SA chain
    linear4_kernel<<<dim3(6, 128), dim3(128), 0, stream>>>(extra, ea_in_w + (size_t)C_ * C_, ea_in_b + C_, s_eakv, C_, 2 * C_, 0);
    // 3. fused self-attn + out-proj + LN -> t1
    sa_fused_kernel<<<dim3(256), dim3(384), 0, stream>>>(s_qkv, tgt, sa_out_w, sa_out_b, ln2_g, ln2_b, s_t1);
    // 4. fused EA (q-proj + attn + out-proj + LN) -> t2
    ea_fused_kernel<<<dim3(256), dim3(384), 0, stream>>>(s_t1, s_eakv, ea_in_w, ea_in_b, ea_out_w, ea_out_b, lne_g, lne_b, s_t2);
    // 5. fused offsets + logits + softmax
    ms_prep_kernel<<<dim3(256), dim3(384), 0, stream>>>(s_t2, ms_off_w, ms_off_b, ms_attn_w, ms_attn_b, s_off, s_aw);
    // 6. deformable gather (per (l,h,row) partials)
    ms_gather_kernel<<<dim3(5, 6, 256), dim3(128), 0, stream>>>(src, refp, vr, s_off, s_aw, s_pagg, s_pws);
    // 7. fused level-reduce + val-proj + out-proj + LN -> t3
    ms_valout_kernel<<<dim3(256), dim3(384), 0, stream>>>(s_pagg, s_pws, ms_val_w, ms_val_b, ms_out_w, ms_out_b, s_t2, ln1_g, ln1_b, s_t3);
    // 8. FFN layer 1 (relu), 4-row tiled
    linear4_kernel<<<dim3(8, 64), dim3(128), 0, stream>>>(s_t3, ffn_w1, ffn_b1, s_h1, C_, DFF_, 1);
    // 9. FFN layer 2, 4-row tiled
    linear4_kernel<<<dim3(3, 64), dim3(128), 0, stream>>>(s_h1, ffn_w2, ffn_b2, s_f2, DFF_, C_, 0);
    // 10. final residual + LN -> out
    add_ln_kernel<<<dim3(256), dim3(64), 0, stream>>>(s_f2, s_t3, ln3_g, ln3_b, (float*)d_out);
}